// Round 5
// baseline (5944.965 us; speedup 1.0000x reference)
//
#include <hip/hip_runtime.h>
#include <math.h>

#define HW 4096   // 64*64

// ---------------------------------------------------------------------------
// bf16 hi/lo split helpers (RN rounding)
// ---------------------------------------------------------------------------
__device__ __host__ inline unsigned short f2bf(float f) {
    unsigned u = __float_as_uint(f);
    unsigned r = (u + 0x7FFFu + ((u >> 16) & 1u)) >> 16;
    return (unsigned short)r;
}
__device__ inline float bf2f(unsigned short h) {
    return __uint_as_float(((unsigned)h) << 16);
}

typedef __attribute__((ext_vector_type(8))) short short8;   // bf16x8 MFMA frag
typedef __attribute__((ext_vector_type(4))) float f32x4;    // MFMA acc frag

__device__ inline float hsig(float x) {
    return fminf(fmaxf(0.2f * x + 0.5f, 0.f), 1.f);
}

// ---------------------------------------------------------------------------
// Weight pre-split: W [tap*C][N] fp32 (HWIO) -> Wt_hi/Wt_lo [tap][N][C] bf16.
// ---------------------------------------------------------------------------
__global__ __launch_bounds__(256) void wsplit(
    const float* __restrict__ W, int C, int N,
    unsigned short* __restrict__ Wh_, unsigned short* __restrict__ Wl_)
{
    int i = blockIdx.x * 256 + threadIdx.x;
    int total = 9 * C * N;
    if (i >= total) return;
    int n = i % N;
    int rc = i / N;
    int tap = rc / C, c = rc % C;
    float v = W[i];
    unsigned short h = f2bf(v);
    unsigned short l = f2bf(v - bf2f(h));
    long o = (long)(tap * N + n) * C + c;
    Wh_[o] = h; Wl_[o] = l;
}

// ---------------------------------------------------------------------------
// B-weight register prefetch (T14): NFRAG hi + NFRAG lo uint4 slots / thread.
// ---------------------------------------------------------------------------
template<int NFRAG>
struct BPre { uint4 h[NFRAG], l[NFRAG]; };

template<int NFRAG>
__device__ inline void prefetchB(int it2, int tid, int cx32, int Cx,
    const unsigned short* __restrict__ Wxh, const unsigned short* __restrict__ Wxl,
    const unsigned short* __restrict__ Whh, const unsigned short* __restrict__ Whl,
    BPre<NFRAG>& bp)
{
    constexpr int N = NFRAG * 64;
    constexpr int F = NFRAG * 16;
    int c0i = it2 / 9, tap = it2 - c0i * 9;
    int src = (c0i >= cx32);
    int c0 = (src ? c0i - cx32 : c0i) << 5;
    const unsigned short* Wth = src ? Whh : Wxh;
    const unsigned short* Wtl = src ? Whl : Wxl;
    int C = src ? F : Cx;
    #pragma unroll
    for (int i = 0; i < NFRAG; ++i) {
        int s = tid + (i << 8);
        int n = s >> 2, g = s & 3;
        long o = (long)(tap * N + n) * C + c0 + (g << 3);
        bp.h[i] = *(const uint4*)(Wth + o);
        bp.l[i] = *(const uint4*)(Wtl + o);
    }
}

// ---------------------------------------------------------------------------
// Fused ConvLSTM step: 3x3 SAME conv over x_t (fp32) and h_{t-1} (fp32),
// hi/lo-split bf16 MFMA (3-term), + in-block LSTM gate epilogue.
// h is double-buffered ACROSS launches (Hs != Hst) — the conv reads a 3x3
// neighborhood of h_{t-1} while h_t is written, so in-place h would race
// across blocks (round-4 bug, absmax 3.7e-3).
// Block: BM=32 positions (half image row), BN=N (all gates). 256 thr / 4 waves.
// A window [3 rows][34 cols][32 ch] staged ONCE per K-chunk; 9 taps read
// shifted LDS cols. XOR-swizzled LDS (16B slot ^ ((row>>1)&3)) both sides.
// ---------------------------------------------------------------------------
template<int NFRAG>   // N = NFRAG*64 (gates), F = NFRAG*16
__global__ __launch_bounds__(256, 2) void conv_lstm_fused(
    const float* __restrict__ X, long xBStride, int Cx,
    const float* __restrict__ Hs,
    const unsigned short* __restrict__ Wxh, const unsigned short* __restrict__ Wxl,
    const unsigned short* __restrict__ Whh, const unsigned short* __restrict__ Whl,
    const float* __restrict__ bias,
    float* __restrict__ Cst, float* __restrict__ Hst,
    float* __restrict__ Out, long outBStride)
{
    constexpr int N  = NFRAG * 64;
    constexpr int F  = NFRAG * 16;
    constexpr int PN = N + 4;           // padded z pitch (floats)
    constexpr int ASH = 3 * 34 * 32;    // shorts per A plane
    constexpr int BSH = N * 32;         // shorts per B plane

    __shared__ __align__(16) unsigned short smem[2 * ASH + 2 * BSH];
    unsigned short* AhL = smem;
    unsigned short* AlL = smem + ASH;
    unsigned short* BhL = smem + 2 * ASH;
    unsigned short* BlL = smem + 2 * ASH + BSH;

    const int tid  = threadIdx.x;
    const int lane = tid & 63;
    const int w    = tid >> 6;
    const int frow = lane & 15;
    const int klane = lane >> 4;
    const int wnbase = w * (NFRAG * 16);

    const int m0   = blockIdx.x << 5;       // 32 positions per block
    const int bimg = m0 >> 12;
    const int y    = (m0 >> 6) & 63;
    const int x0   = m0 & 63;               // 0 or 32

    const int cx32 = Cx >> 5;
    constexpr int f32c = NFRAG >> 1;        // F/32
    const int total = (cx32 + f32c) * 9;

    f32x4 acc[2][NFRAG] = {};

    BPre<NFRAG> bp;
    prefetchB<NFRAG>(0, tid, cx32, Cx, Wxh, Wxl, Whh, Whl, bp);

    #pragma unroll 1
    for (int it = 0; it < total; ++it) {
        int c0i = it / 9, tap = it - c0i * 9;
        int src = (c0i >= cx32);
        int c0  = (src ? c0i - cx32 : c0i) << 5;
        int C   = src ? F : Cx;
        int ky  = tap / 3, kx = tap - ky * 3;

        __syncthreads();                    // previous LDS readers done
        if (tap == 0) {
            // ---- stage A window: 3 rows x 34 cols x 32 ch, split hi/lo ----
            const float* Sb = src ? (Hs + (long)bimg * HW * F)
                                  : (X  + (long)bimg * xBStride);
            #pragma unroll
            for (int i = 0; i < 4; ++i) {
                int s = tid + (i << 8);
                if (s < 816) {              // 3*34*8 slots of 4 fp32
                    int r = s / 272, rem = s - r * 272;
                    int q = rem >> 3, g4 = rem & 7;
                    int xx = x0 - 1 + q, yy = y + r - 1;
                    float4 v = make_float4(0.f, 0.f, 0.f, 0.f);
                    if ((unsigned)xx < 64u && (unsigned)yy < 64u)
                        v = *(const float4*)(Sb + (long)((yy << 6) + xx) * C
                                             + c0 + (g4 << 2));
                    unsigned short h0 = f2bf(v.x), h1 = f2bf(v.y),
                                   h2 = f2bf(v.z), h3 = f2bf(v.w);
                    unsigned short l0 = f2bf(v.x - bf2f(h0)),
                                   l1 = f2bf(v.y - bf2f(h1)),
                                   l2 = f2bf(v.z - bf2f(h2)),
                                   l3 = f2bf(v.w - bf2f(h3));
                    uint2 hw2 = make_uint2((unsigned)h0 | ((unsigned)h1 << 16),
                                           (unsigned)h2 | ((unsigned)h3 << 16));
                    uint2 lw2 = make_uint2((unsigned)l0 | ((unsigned)l1 << 16),
                                           (unsigned)l2 | ((unsigned)l3 << 16));
                    int idx = ((r * 34 + q) << 5)
                            + (((g4 >> 1) ^ ((q >> 1) & 3)) << 3)
                            + ((g4 & 1) << 2);
                    *(uint2*)&AhL[idx] = hw2;
                    *(uint2*)&AlL[idx] = lw2;
                }
            }
        }
        // ---- write prefetched B to LDS (swizzled) ----
        #pragma unroll
        for (int i = 0; i < NFRAG; ++i) {
            int s = tid + (i << 8);
            int n = s >> 2, g = s & 3;
            int idx = (n << 5) + ((g ^ ((n >> 1) & 3)) << 3);
            *(uint4*)&BhL[idx] = bp.h[i];
            *(uint4*)&BlL[idx] = bp.l[i];
        }
        __syncthreads();
        // ---- issue next B prefetch (lands under the MFMAs below) ----
        if (it + 1 < total)
            prefetchB<NFRAG>(it + 1, tid, cx32, Cx, Wxh, Wxl, Whh, Whl, bp);

        // ---- fragments + MFMAs for this tap ----
        short8 fah[2], fal[2], fbh[NFRAG], fbl[NFRAG];
        #pragma unroll
        for (int mf = 0; mf < 2; ++mf) {
            int q = (mf << 4) + frow + kx;
            int idx = ((ky * 34 + q) << 5) + ((klane ^ ((q >> 1) & 3)) << 3);
            fah[mf] = *(const short8*)&AhL[idx];
            fal[mf] = *(const short8*)&AlL[idx];
        }
        #pragma unroll
        for (int nf = 0; nf < NFRAG; ++nf) {
            int n = wnbase + (nf << 4) + frow;
            int idx = (n << 5) + ((klane ^ ((n >> 1) & 3)) << 3);
            fbh[nf] = *(const short8*)&BhL[idx];
            fbl[nf] = *(const short8*)&BlL[idx];
        }
        #pragma unroll
        for (int mf = 0; mf < 2; ++mf)
            #pragma unroll
            for (int nf = 0; nf < NFRAG; ++nf) {
                acc[mf][nf] = __builtin_amdgcn_mfma_f32_16x16x32_bf16(
                    fah[mf], fbh[nf], acc[mf][nf], 0, 0, 0);
                acc[mf][nf] = __builtin_amdgcn_mfma_f32_16x16x32_bf16(
                    fah[mf], fbl[nf], acc[mf][nf], 0, 0, 0);
                acc[mf][nf] = __builtin_amdgcn_mfma_f32_16x16x32_bf16(
                    fal[mf], fbh[nf], acc[mf][nf], 0, 0, 0);
            }
    }

    // ---- epilogue: acc -> LDS z tile -> fused LSTM gates ----
    __syncthreads();                        // all MFMA LDS reads done
    float* zl = (float*)smem;
    #pragma unroll
    for (int mf = 0; mf < 2; ++mf)
        #pragma unroll
        for (int nf = 0; nf < NFRAG; ++nf)
            #pragma unroll
            for (int r = 0; r < 4; ++r)
                zl[((mf << 4) + (klane << 2) + r) * PN
                   + wnbase + (nf << 4) + frow] = acc[mf][nf][r];
    __syncthreads();

    constexpr int NF4 = F >> 2;             // float4 groups per row
    constexpr int LG  = (NFRAG == 4) ? 4 : 3;
    #pragma unroll
    for (int s0 = 0; s0 < 32 * NF4; s0 += 256) {
        int s = s0 + tid;
        int m = s >> LG, f = (s & (NF4 - 1)) << 2;
        const float* zr = &zl[m * PN];
        float4 zi = *(const float4*)&zr[f];
        float4 zf = *(const float4*)&zr[f + F];
        float4 zg = *(const float4*)&zr[f + 2 * F];
        float4 zo = *(const float4*)&zr[f + 3 * F];
        float4 bi = *(const float4*)&bias[f];
        float4 bfv = *(const float4*)&bias[f + F];
        float4 bg = *(const float4*)&bias[f + 2 * F];
        float4 bo = *(const float4*)&bias[f + 3 * F];
        long pos = m0 + m;
        float4 c = *(const float4*)&Cst[pos * F + f];
        float4 hv, ov;
#define GATE(comp) { \
        float iv = hsig(zi.comp + bi.comp); \
        float fv = hsig(zf.comp + bfv.comp); \
        float gv = tanhf(zg.comp + bg.comp); \
        float og = hsig(zo.comp + bo.comp); \
        float cn = fv * c.comp + iv * gv; \
        float hn = og * tanhf(cn); \
        c.comp = cn; hv.comp = hn; ov.comp = fmaxf(hn, 0.f); }
        GATE(x) GATE(y) GATE(z) GATE(w)
#undef GATE
        *(float4*)&Cst[pos * F + f] = c;
        *(float4*)&Hst[pos * F + f] = hv;
        int bb = (int)(pos >> 12), p = (int)(pos & 4095);
        *(float4*)&Out[(long)bb * outBStride + (long)p * F + f] = ov;
    }
}

// ---------------------------------------------------------------------------
// Host: 3 layers x 16 timesteps, one fused kernel per step. h ping-pongs
// between h0/h1 across timesteps (conv reads neighborhood of h_{t-1}, so
// in-place update races across blocks). c updates in place (position-local).
// d_out doubles as layer-1 seq buffer [T,B,HW,64]; dead after layer 2.
// ws: seq2 (32 MB) + h0/h1/c (12 MB) + split weights (2.5 MB).
// ---------------------------------------------------------------------------
extern "C" void kernel_launch(void* const* d_in, const int* in_sizes, int n_in,
                              void* d_out, int out_size, void* d_ws, size_t ws_size,
                              hipStream_t stream)
{
    const float* x   = (const float*)d_in[0];
    const float* Wx1 = (const float*)d_in[1];
    const float* Wh1 = (const float*)d_in[2];
    const float* b1  = (const float*)d_in[3];
    const float* Wx2 = (const float*)d_in[4];
    const float* Wh2 = (const float*)d_in[5];
    const float* b2  = (const float*)d_in[6];
    const float* Wx3 = (const float*)d_in[7];
    const float* Wh3 = (const float*)d_in[8];
    const float* b3  = (const float*)d_in[9];
    float* out = (float*)d_out;
    float* ws  = (float*)d_ws;

    const int T = 16, B = 4;
    float* seq2 = ws;                   // 16*4*4096*32 = 8,388,608 floats
    float* h0   = ws + 8388608;         // 1,048,576
    float* h1   = ws + 9437184;         // 1,048,576
    float* cbuf = ws + 10485760;        // 1,048,576
    unsigned short* wt = (unsigned short*)(ws + 11534336);

    struct WSz { const float* W; int C, N; };
    WSz wsrc[6] = {
        { Wx1, 64, 256 }, { Wh1, 64, 256 },
        { Wx2, 64, 128 }, { Wh2, 32, 128 },
        { Wx3, 32, 256 }, { Wh3, 64, 256 },
    };
    unsigned short* Wsp[6][2];
    {
        long off = 0;
        for (int i = 0; i < 6; ++i) {
            long sz = 9L * wsrc[i].C * wsrc[i].N;
            Wsp[i][0] = wt + off; off += sz;
            Wsp[i][1] = wt + off; off += sz;
        }
        for (int i = 0; i < 6; ++i) {
            int total = 9 * wsrc[i].C * wsrc[i].N;
            wsplit<<<(total + 255) / 256, 256, 0, stream>>>(
                wsrc[i].W, wsrc[i].C, wsrc[i].N, Wsp[i][0], Wsp[i][1]);
        }
    }

    struct L {
        int wi; const float* bias; int Cx, F;
        const float* in0; long inT, inB;
        float* out0; long outT, outB;
    };
    L ls[3] = {
        { 0, b1, 64, 64, x,    (long)HW * 64, (long)T * HW * 64,
          out,  (long)B * HW * 64, (long)HW * 64 },
        { 2, b2, 64, 32, out,  (long)B * HW * 64, (long)HW * 64,
          seq2, (long)B * HW * 32, (long)HW * 32 },
        { 4, b3, 32, 64, seq2, (long)B * HW * 32, (long)HW * 32,
          out,  (long)HW * 64, (long)T * HW * 64 },
    };

    for (int l = 0; l < 3; ++l) {
        const L& P = ls[l];
        hipMemsetAsync(h0,   0, (size_t)B * HW * P.F * sizeof(float), stream);
        hipMemsetAsync(cbuf, 0, (size_t)B * HW * P.F * sizeof(float), stream);
        for (int t = 0; t < T; ++t) {
            float* hread  = (t & 1) ? h1 : h0;
            float* hwrite = (t & 1) ? h0 : h1;
            if (P.F == 64) {
                conv_lstm_fused<4><<<B * HW / 32, 256, 0, stream>>>(
                    P.in0 + (long)t * P.inT, P.inB, P.Cx, hread,
                    Wsp[P.wi][0], Wsp[P.wi][1], Wsp[P.wi + 1][0], Wsp[P.wi + 1][1],
                    P.bias, cbuf, hwrite,
                    P.out0 + (long)t * P.outT, P.outB);
            } else {
                conv_lstm_fused<2><<<B * HW / 32, 256, 0, stream>>>(
                    P.in0 + (long)t * P.inT, P.inB, P.Cx, hread,
                    Wsp[P.wi][0], Wsp[P.wi][1], Wsp[P.wi + 1][0], Wsp[P.wi + 1][1],
                    P.bias, cbuf, hwrite,
                    P.out0 + (long)t * P.outT, P.outB);
            }
        }
    }
}

// Round 6
// 1722.218 us; speedup vs baseline: 3.4519x; 3.4519x over previous
//
#include <hip/hip_runtime.h>
#include <math.h>

#define HW 4096   // 64*64

// ---------------------------------------------------------------------------
// bf16 hi/lo split helpers (RN rounding)
// ---------------------------------------------------------------------------
__device__ __host__ inline unsigned short f2bf(float f) {
    unsigned u = __float_as_uint(f);
    unsigned r = (u + 0x7FFFu + ((u >> 16) & 1u)) >> 16;
    return (unsigned short)r;
}
__device__ inline float bf2f(unsigned short h) {
    return __uint_as_float(((unsigned)h) << 16);
}

typedef __attribute__((ext_vector_type(8))) short short8;   // bf16x8 MFMA frag
typedef __attribute__((ext_vector_type(4))) float f32x4;    // MFMA acc frag

__device__ inline float hsig(float x) {
    return fminf(fmaxf(0.2f * x + 0.5f, 0.f), 1.f);
}

// async global->LDS, 16B per lane (zero VGPR cost, no ds_write)
typedef __attribute__((address_space(3))) unsigned int lds_u32_t;
typedef __attribute__((address_space(1))) const unsigned int glb_u32_t;
__device__ inline void g2l16(const unsigned short* g, unsigned short* l) {
    __builtin_amdgcn_global_load_lds((glb_u32_t*)g, (lds_u32_t*)l, 16, 0, 0);
}

// ---------------------------------------------------------------------------
// Weight pre-split + PERMUTE: W [tap*C][N] fp32 (HWIO) -> hi/lo bf16 in the
// exact linear order that global_load_lds deposits into the swizzled LDS
// B-tile. For (tap, 32-ch chunk ch): 16B slot s = n*4 + g' holds k-group
// g = g' ^ ((n>>1)&3) of row n  (so LDS slot s*16B == swizzled [n][g]).
// ---------------------------------------------------------------------------
__global__ __launch_bounds__(256) void wsplit(
    const float* __restrict__ W, int C, int N,
    unsigned short* __restrict__ Wh_, unsigned short* __restrict__ Wl_)
{
    int i = blockIdx.x * 256 + threadIdx.x;
    int total = 9 * C * N;
    if (i >= total) return;
    int n = i % N;
    int rc = i / N;
    int tap = rc / C, c = rc % C;
    float v = W[i];
    unsigned short h = f2bf(v);
    unsigned short l = f2bf(v - bf2f(h));
    int ch = c >> 5, kl = c & 31, g = kl >> 3, e = kl & 7;
    int gp = g ^ ((n >> 1) & 3);
    int nch = C >> 5;
    long o = ((long)(tap * nch + ch) * (N << 2) + ((n << 2) + gp)) * 8 + e;
    Wh_[o] = h; Wl_[o] = l;
}

// ---------------------------------------------------------------------------
// Fused ConvLSTM step: 3x3 SAME conv over x_t (fp32) and h_{t-1} (fp32),
// hi/lo-split bf16 MFMA (3-term), + in-block LSTM gate epilogue.
// h is double-buffered ACROSS launches (Hs != Hst): conv reads a 3x3
// neighborhood of h_{t-1}, in-place update races across blocks.
// Block: BM=32 positions (half image row), BN=N (all gates). 256 thr / 4 waves.
// A window [3 rows][34 cols][32 ch] staged once per 9 taps (ds_write, hi/lo
// split in VALU); B weights arrive via global_load_lds into pre-swizzled
// slots (permuted in wsplit) — no VGPR staging, no spills (round-5 lesson:
// register B-prefetch spilled ~186 MB/dispatch of scratch writes).
// ---------------------------------------------------------------------------
template<int NFRAG>   // N = NFRAG*64 (gates), F = NFRAG*16
__global__ __launch_bounds__(256, 2) void conv_lstm_fused(
    const float* __restrict__ X, long xBStride, int Cx,
    const float* __restrict__ Hs,
    const unsigned short* __restrict__ Wxh, const unsigned short* __restrict__ Wxl,
    const unsigned short* __restrict__ Whh, const unsigned short* __restrict__ Whl,
    const float* __restrict__ bias,
    float* __restrict__ Cst, float* __restrict__ Hst,
    float* __restrict__ Out, long outBStride)
{
    constexpr int N  = NFRAG * 64;
    constexpr int F  = NFRAG * 16;
    constexpr int PN = N + 4;           // padded z pitch (floats)
    constexpr int ASH = 3 * 34 * 32;    // shorts per A plane
    constexpr int BSH = N * 32;         // shorts per B plane

    __shared__ __align__(16) unsigned short smem[2 * ASH + 2 * BSH];
    unsigned short* AhL = smem;
    unsigned short* AlL = smem + ASH;
    unsigned short* BhL = smem + 2 * ASH;
    unsigned short* BlL = smem + 2 * ASH + BSH;

    const int tid  = threadIdx.x;
    const int lane = tid & 63;
    const int w    = tid >> 6;
    const int frow = lane & 15;
    const int klane = lane >> 4;
    const int wnbase = w * (NFRAG * 16);

    const int m0   = blockIdx.x << 5;       // 32 positions per block
    const int bimg = m0 >> 12;
    const int y    = (m0 >> 6) & 63;
    const int x0   = m0 & 63;               // 0 or 32

    const int cx32 = Cx >> 5;
    constexpr int f32c = NFRAG >> 1;        // F/32
    const int total = (cx32 + f32c) * 9;

    f32x4 acc[2][NFRAG] = {};

    #pragma unroll 1
    for (int it = 0; it < total; ++it) {
        int c0i = it / 9, tap = it - c0i * 9;
        int src = (c0i >= cx32);
        int ch  = src ? c0i - cx32 : c0i;
        int c0  = ch << 5;
        int C   = src ? F : Cx;
        int nch = src ? f32c : cx32;
        int ky  = tap / 3, kx = tap - ky * 3;

        __syncthreads();                    // previous LDS readers done

        // ---- B: async global->LDS, pre-permuted so linear deposit is
        //      already the swizzled layout ----
        {
            const unsigned short* Wth = src ? Whh : Wxh;
            const unsigned short* Wtl = src ? Whl : Wxl;
            const long pbase = (long)(tap * nch + ch) * (N << 2) * 8;
            #pragma unroll
            for (int i = 0; i < NFRAG; ++i) {
                int s = tid + (i << 8);
                g2l16(Wth + pbase + s * 8, &BhL[s * 8]);
                g2l16(Wtl + pbase + s * 8, &BlL[s * 8]);
            }
        }

        if (tap == 0) {
            // ---- stage A window: 3 rows x 34 cols x 32 ch, split hi/lo ----
            const float* Sb = src ? (Hs + (long)bimg * HW * F)
                                  : (X  + (long)bimg * xBStride);
            #pragma unroll
            for (int i = 0; i < 4; ++i) {
                int s = tid + (i << 8);
                if (s < 816) {              // 3*34*8 slots of 4 fp32
                    int r = s / 272, rem = s - r * 272;
                    int q = rem >> 3, g4 = rem & 7;
                    int xx = x0 - 1 + q, yy = y + r - 1;
                    float4 v = make_float4(0.f, 0.f, 0.f, 0.f);
                    if ((unsigned)xx < 64u && (unsigned)yy < 64u)
                        v = *(const float4*)(Sb + (long)((yy << 6) + xx) * C
                                             + c0 + (g4 << 2));
                    unsigned short h0 = f2bf(v.x), h1 = f2bf(v.y),
                                   h2 = f2bf(v.z), h3 = f2bf(v.w);
                    unsigned short l0 = f2bf(v.x - bf2f(h0)),
                                   l1 = f2bf(v.y - bf2f(h1)),
                                   l2 = f2bf(v.z - bf2f(h2)),
                                   l3 = f2bf(v.w - bf2f(h3));
                    uint2 hw2 = make_uint2((unsigned)h0 | ((unsigned)h1 << 16),
                                           (unsigned)h2 | ((unsigned)h3 << 16));
                    uint2 lw2 = make_uint2((unsigned)l0 | ((unsigned)l1 << 16),
                                           (unsigned)l2 | ((unsigned)l3 << 16));
                    int idx = ((r * 34 + q) << 5)
                            + (((g4 >> 1) ^ ((q >> 1) & 3)) << 3)
                            + ((g4 & 1) << 2);
                    *(uint2*)&AhL[idx] = hw2;
                    *(uint2*)&AlL[idx] = lw2;
                }
            }
        }
        __syncthreads();    // drains vmcnt (B landed) + lgkm (A written)

        // ---- fragments + MFMAs for this tap ----
        short8 fah[2], fal[2], fbh[NFRAG], fbl[NFRAG];
        #pragma unroll
        for (int mf = 0; mf < 2; ++mf) {
            int q = (mf << 4) + frow + kx;
            int idx = ((ky * 34 + q) << 5) + ((klane ^ ((q >> 1) & 3)) << 3);
            fah[mf] = *(const short8*)&AhL[idx];
            fal[mf] = *(const short8*)&AlL[idx];
        }
        #pragma unroll
        for (int nf = 0; nf < NFRAG; ++nf) {
            int n = wnbase + (nf << 4) + frow;
            int idx = (n << 5) + ((klane ^ ((n >> 1) & 3)) << 3);
            fbh[nf] = *(const short8*)&BhL[idx];
            fbl[nf] = *(const short8*)&BlL[idx];
        }
        #pragma unroll
        for (int mf = 0; mf < 2; ++mf)
            #pragma unroll
            for (int nf = 0; nf < NFRAG; ++nf) {
                acc[mf][nf] = __builtin_amdgcn_mfma_f32_16x16x32_bf16(
                    fah[mf], fbh[nf], acc[mf][nf], 0, 0, 0);
                acc[mf][nf] = __builtin_amdgcn_mfma_f32_16x16x32_bf16(
                    fah[mf], fbl[nf], acc[mf][nf], 0, 0, 0);
                acc[mf][nf] = __builtin_amdgcn_mfma_f32_16x16x32_bf16(
                    fal[mf], fbh[nf], acc[mf][nf], 0, 0, 0);
            }
    }

    // ---- epilogue: acc -> LDS z tile -> fused LSTM gates ----
    __syncthreads();                        // all MFMA LDS reads done
    float* zl = (float*)smem;
    #pragma unroll
    for (int mf = 0; mf < 2; ++mf)
        #pragma unroll
        for (int nf = 0; nf < NFRAG; ++nf)
            #pragma unroll
            for (int r = 0; r < 4; ++r)
                zl[((mf << 4) + (klane << 2) + r) * PN
                   + wnbase + (nf << 4) + frow] = acc[mf][nf][r];
    __syncthreads();

    constexpr int NF4 = F >> 2;             // float4 groups per row
    constexpr int LG  = (NFRAG == 4) ? 4 : 3;
    #pragma unroll
    for (int s0 = 0; s0 < 32 * NF4; s0 += 256) {
        int s = s0 + tid;
        int m = s >> LG, f = (s & (NF4 - 1)) << 2;
        const float* zr = &zl[m * PN];
        float4 zi = *(const float4*)&zr[f];
        float4 zf = *(const float4*)&zr[f + F];
        float4 zg = *(const float4*)&zr[f + 2 * F];
        float4 zo = *(const float4*)&zr[f + 3 * F];
        float4 bi = *(const float4*)&bias[f];
        float4 bfv = *(const float4*)&bias[f + F];
        float4 bg = *(const float4*)&bias[f + 2 * F];
        float4 bo = *(const float4*)&bias[f + 3 * F];
        long pos = m0 + m;
        float4 c = *(const float4*)&Cst[pos * F + f];
        float4 hv, ov;
#define GATE(comp) { \
        float iv = hsig(zi.comp + bi.comp); \
        float fv = hsig(zf.comp + bfv.comp); \
        float gv = tanhf(zg.comp + bg.comp); \
        float og = hsig(zo.comp + bo.comp); \
        float cn = fv * c.comp + iv * gv; \
        float hn = og * tanhf(cn); \
        c.comp = cn; hv.comp = hn; ov.comp = fmaxf(hn, 0.f); }
        GATE(x) GATE(y) GATE(z) GATE(w)
#undef GATE
        *(float4*)&Cst[pos * F + f] = c;
        *(float4*)&Hst[pos * F + f] = hv;
        int bb = (int)(pos >> 12), p = (int)(pos & 4095);
        *(float4*)&Out[(long)bb * outBStride + (long)p * F + f] = ov;
    }
}

// ---------------------------------------------------------------------------
// Host: 3 layers x 16 timesteps, one fused kernel per step. h ping-pongs
// between h0/h1 across timesteps; c updates in place (position-local).
// d_out doubles as layer-1 seq buffer [T,B,HW,64]; dead after layer 2.
// ws: seq2 (32 MB) + h0/h1/c (12 MB) + split weights (2.5 MB).
// ---------------------------------------------------------------------------
extern "C" void kernel_launch(void* const* d_in, const int* in_sizes, int n_in,
                              void* d_out, int out_size, void* d_ws, size_t ws_size,
                              hipStream_t stream)
{
    const float* x   = (const float*)d_in[0];
    const float* Wx1 = (const float*)d_in[1];
    const float* Wh1 = (const float*)d_in[2];
    const float* b1  = (const float*)d_in[3];
    const float* Wx2 = (const float*)d_in[4];
    const float* Wh2 = (const float*)d_in[5];
    const float* b2  = (const float*)d_in[6];
    const float* Wx3 = (const float*)d_in[7];
    const float* Wh3 = (const float*)d_in[8];
    const float* b3  = (const float*)d_in[9];
    float* out = (float*)d_out;
    float* ws  = (float*)d_ws;

    const int T = 16, B = 4;
    float* seq2 = ws;                   // 16*4*4096*32 = 8,388,608 floats
    float* h0   = ws + 8388608;         // 1,048,576
    float* h1   = ws + 9437184;         // 1,048,576
    float* cbuf = ws + 10485760;        // 1,048,576
    unsigned short* wt = (unsigned short*)(ws + 11534336);

    struct WSz { const float* W; int C, N; };
    WSz wsrc[6] = {
        { Wx1, 64, 256 }, { Wh1, 64, 256 },
        { Wx2, 64, 128 }, { Wh2, 32, 128 },
        { Wx3, 32, 256 }, { Wh3, 64, 256 },
    };
    unsigned short* Wsp[6][2];
    {
        long off = 0;
        for (int i = 0; i < 6; ++i) {
            long sz = 9L * wsrc[i].C * wsrc[i].N;
            Wsp[i][0] = wt + off; off += sz;
            Wsp[i][1] = wt + off; off += sz;
        }
        for (int i = 0; i < 6; ++i) {
            int total = 9 * wsrc[i].C * wsrc[i].N;
            wsplit<<<(total + 255) / 256, 256, 0, stream>>>(
                wsrc[i].W, wsrc[i].C, wsrc[i].N, Wsp[i][0], Wsp[i][1]);
        }
    }

    struct L {
        int wi; const float* bias; int Cx, F;
        const float* in0; long inT, inB;
        float* out0; long outT, outB;
    };
    L ls[3] = {
        { 0, b1, 64, 64, x,    (long)HW * 64, (long)T * HW * 64,
          out,  (long)B * HW * 64, (long)HW * 64 },
        { 2, b2, 64, 32, out,  (long)B * HW * 64, (long)HW * 64,
          seq2, (long)B * HW * 32, (long)HW * 32 },
        { 4, b3, 32, 64, seq2, (long)B * HW * 32, (long)HW * 32,
          out,  (long)HW * 64, (long)T * HW * 64 },
    };

    for (int l = 0; l < 3; ++l) {
        const L& P = ls[l];
        hipMemsetAsync(h0,   0, (size_t)B * HW * P.F * sizeof(float), stream);
        hipMemsetAsync(cbuf, 0, (size_t)B * HW * P.F * sizeof(float), stream);
        for (int t = 0; t < T; ++t) {
            float* hread  = (t & 1) ? h1 : h0;
            float* hwrite = (t & 1) ? h0 : h1;
            if (P.F == 64) {
                conv_lstm_fused<4><<<B * HW / 32, 256, 0, stream>>>(
                    P.in0 + (long)t * P.inT, P.inB, P.Cx, hread,
                    Wsp[P.wi][0], Wsp[P.wi][1], Wsp[P.wi + 1][0], Wsp[P.wi + 1][1],
                    P.bias, cbuf, hwrite,
                    P.out0 + (long)t * P.outT, P.outB);
            } else {
                conv_lstm_fused<2><<<B * HW / 32, 256, 0, stream>>>(
                    P.in0 + (long)t * P.inT, P.inB, P.Cx, hread,
                    Wsp[P.wi][0], Wsp[P.wi][1], Wsp[P.wi + 1][0], Wsp[P.wi + 1][1],
                    P.bias, cbuf, hwrite,
                    P.out0 + (long)t * P.outT, P.outB);
            }
        }
    }
}